// Round 4
// baseline (1426.296 us; speedup 1.0000x reference)
//
#include <hip/hip_runtime.h>
#include <cstdint>
#include <cstddef>

// Problem constants
#define BATCH   4
#define L_SEQ   2048
#define DMODEL  1024
#define NHEAD   4
#define HDIM    256
#define FFDIM   4096
#define MROWS   (BATCH * L_SEQ)   // 8192
#define NLAYER  2

typedef __bf16 bf16_t;
typedef __bf16 bf16x8 __attribute__((ext_vector_type(8)));
typedef __bf16 bf16x4 __attribute__((ext_vector_type(4)));
typedef float  floatx4 __attribute__((ext_vector_type(4)));

// ---------------------------------------------------------------------------
// async global->LDS 16B copy. LDS dest = wave-uniform base + lane*16 (HW rule).
// ---------------------------------------------------------------------------
__device__ __forceinline__ void async_cp16(const void* g, void* l) {
  auto gp = reinterpret_cast<__attribute__((address_space(1))) void*>(
      reinterpret_cast<uintptr_t>(g));
  auto lp = reinterpret_cast<__attribute__((address_space(3))) void*>(
      reinterpret_cast<uintptr_t>(l));
  __builtin_amdgcn_global_load_lds(gp, lp, 16, 0, 0);
}

// ---------------------------------------------------------------------------
// f32 -> bf16 convert (vectorized)
// ---------------------------------------------------------------------------
__global__ __launch_bounds__(256)
void cvt_f32_bf16(const float* __restrict__ in, bf16_t* __restrict__ out, int n4) {
  int i = blockIdx.x * 256 + threadIdx.x;
  if (i >= n4) return;
  float4 v = ((const float4*)in)[i];
  bf16x4 ov = { (bf16_t)v.x, (bf16_t)v.y, (bf16_t)v.z, (bf16_t)v.w };
  ((bf16x4*)out)[i] = ov;
}

// ---------------------------------------------------------------------------
// LayerNorm: one block (256 threads) per row of D=1024, fp32 math.
// ---------------------------------------------------------------------------
template<bool BF16OUT>
__global__ __launch_bounds__(256)
void ln_kernel(const float* __restrict__ x, const float* __restrict__ gw,
               const float* __restrict__ bw, void* __restrict__ outp) {
  const int row = blockIdx.x;
  const int tid = threadIdx.x;
  const float4 v = ((const float4*)(x + (size_t)row * DMODEL))[tid];
  float s  = v.x + v.y + v.z + v.w;
  float ss = v.x * v.x + v.y * v.y + v.z * v.z + v.w * v.w;
#pragma unroll
  for (int o = 32; o > 0; o >>= 1) {
    s  += __shfl_xor(s, o);
    ss += __shfl_xor(ss, o);
  }
  __shared__ float red0[4], red1[4];
  const int wv = tid >> 6;
  if ((tid & 63) == 0) { red0[wv] = s; red1[wv] = ss; }
  __syncthreads();
  s  = red0[0] + red0[1] + red0[2] + red0[3];
  ss = red1[0] + red1[1] + red1[2] + red1[3];
  const float mu  = s * (1.0f / DMODEL);
  const float var = ss * (1.0f / DMODEL) - mu * mu;
  const float rs  = rsqrtf(var + 1e-5f);
  const float4 g4 = ((const float4*)gw)[tid];
  const float4 b4 = ((const float4*)bw)[tid];
  const float o0 = (v.x - mu) * rs * g4.x + b4.x;
  const float o1 = (v.y - mu) * rs * g4.y + b4.y;
  const float o2 = (v.z - mu) * rs * g4.z + b4.z;
  const float o3 = (v.w - mu) * rs * g4.w + b4.w;
  if (BF16OUT) {
    bf16x4 ov = { (bf16_t)o0, (bf16_t)o1, (bf16_t)o2, (bf16_t)o3 };
    ((bf16x4*)outp)[(size_t)row * (DMODEL / 4) + tid] = ov;
  } else {
    float4 ov = { o0, o1, o2, o3 };
    ((float4*)outp)[(size_t)row * (DMODEL / 4) + tid] = ov;
  }
}

// ---------------------------------------------------------------------------
// Flash attention, key-split. Grid (16 q-tiles, 16 z, 2 key-halves), 256 thr
// = 4 waves. Each wave owns 32 q-rows as two 16-q groups; every K/V LDS frag
// read feeds 2 MFMAs (halves LDS traffic vs 1 frag:1 MFMA). 2 blocks/CU.
// Outputs UNNORMALIZED partial O (fp32) + per-row (m, l) for exact combine.
// Per 64-key iteration:
//   stage K-tile (64x256) + V^T-tile (256x64) via swizzled global_load_lds,
//   S^T = K @ Q^T (two q-groups), online softmax fp32,
//   P (bf16) overlaid into K region, O^T += V^T @ P (two q-groups).
// ---------------------------------------------------------------------------
__global__ __launch_bounds__(256, 2)
void flash_attn(const bf16_t* __restrict__ Q, const bf16_t* __restrict__ K,
                const bf16_t* __restrict__ VT, float* __restrict__ Opart,
                float* __restrict__ ml) {
  __shared__ bf16_t lsK[64 * 256];   // 32KB; P (4 waves x 2 groups x 2KB) overlays
  __shared__ bf16_t lsV[256 * 64];   // 32KB (V^T tile: row=hd, col=key)
  const int tid = threadIdx.x, wave = tid >> 6, lane = tid & 63;
  const int lane15 = lane & 15, quad = lane >> 4;
  const int z = blockIdx.y, qt = blockIdx.x, h = blockIdx.z;
  const bf16_t* Qz = Q + (size_t)z * L_SEQ * HDIM;
  const bf16_t* Kz = K + ((size_t)z * L_SEQ + h * 1024) * HDIM;
  const bf16_t* Vz = VT + (size_t)z * HDIM * L_SEQ + h * 1024;
  float* Op = Opart + (size_t)h * MROWS * DMODEL;

  // Q fragments for 2 q-groups: B[n=lane15][k=quad*8+j], 8 k-chunks of 32
  bf16x8 qf[2][8];
#pragma unroll
  for (int g = 0; g < 2; ++g) {
    const int qrow = qt * 128 + wave * 32 + g * 16 + lane15;
#pragma unroll
    for (int kc = 0; kc < 8; ++kc)
      qf[g][kc] =
          *(const bf16x8*)(Qz + (size_t)qrow * HDIM + kc * 32 + quad * 8);
  }

  floatx4 oacc[2][16] = {};     // O^T[hd=mf*16+quad*4+r][q=lane15] per group
  float m_run[2] = {-1e30f, -1e30f}, l_run[2] = {0.f, 0.f};

  const int krl = lane >> 5, kp = lane & 31;   // K: 2 rows/instr, 32 chunks/row
  const int vrl = lane >> 3, vp = lane & 7;    // V: 8 rows/instr, 8 chunks/row

  for (int kt = 0; kt < 1024; kt += 64) {
    // ---- stage K-tile + V^T-tile (16 async_cp16 per wave) ----
#pragma unroll
    for (int j = 0; j < 8; ++j) {
      const int i = wave * 8 + j;
      const int r = 2 * i + krl;
      const int col = ((kp & 24) | ((kp ^ r) & 7)) * 8;
      async_cp16(Kz + (size_t)(kt + r) * HDIM + col, lsK + i * 512);
      const int rv = 8 * i + vrl;
      const int colv = ((vp ^ rv) & 7) * 8;
      async_cp16(Vz + (size_t)rv * L_SEQ + kt + colv, lsV + i * 512);
    }
    __syncthreads();

    // ---- S^T = K @ Q^T, both q-groups share each K fragment ----
    floatx4 sacc[2][4] = {};
#pragma unroll
    for (int kc = 0; kc < 8; ++kc) {
#pragma unroll
      for (int mf = 0; mf < 4; ++mf) {
        const int rr = mf * 16 + lane15;
        const int c = kc * 4 + quad;
        const int phys = (c & 24) | ((c ^ rr) & 7);
        bf16x8 af = *(const bf16x8*)(lsK + rr * 256 + phys * 8);
        sacc[0][mf] = __builtin_amdgcn_mfma_f32_16x16x32_bf16(af, qf[0][kc],
                                                              sacc[0][mf], 0, 0, 0);
        sacc[1][mf] = __builtin_amdgcn_mfma_f32_16x16x32_bf16(af, qf[1][kc],
                                                              sacc[1][mf], 0, 0, 0);
      }
    }

    // ---- online softmax per group (q = lane15; keys over quads+regs) ----
    bf16x4 pk[2][4];
#pragma unroll
    for (int g = 0; g < 2; ++g) {
      float p[4][4];
      float mx = -1e30f;
#pragma unroll
      for (int mf = 0; mf < 4; ++mf)
#pragma unroll
        for (int r = 0; r < 4; ++r) {
          p[mf][r] = sacc[g][mf][r] * 0.0625f;   // 1/sqrt(256)
          mx = fmaxf(mx, p[mf][r]);
        }
      mx = fmaxf(mx, __shfl_xor(mx, 16));
      mx = fmaxf(mx, __shfl_xor(mx, 32));
      const float m_new = fmaxf(m_run[g], mx);
      const float alpha = __expf(m_run[g] - m_new);
      float rs = 0.f;
#pragma unroll
      for (int mf = 0; mf < 4; ++mf) {
#pragma unroll
        for (int r = 0; r < 4; ++r) {
          p[mf][r] = __expf(p[mf][r] - m_new);
          rs += p[mf][r];
        }
        pk[g][mf] = bf16x4{ (bf16_t)p[mf][0], (bf16_t)p[mf][1],
                            (bf16_t)p[mf][2], (bf16_t)p[mf][3] };
      }
      rs += __shfl_xor(rs, 16);
      rs += __shfl_xor(rs, 32);
      l_run[g] = l_run[g] * alpha + rs;
      m_run[g] = m_new;
#pragma unroll
      for (int mf = 0; mf < 16; ++mf)
#pragma unroll
        for (int r = 0; r < 4; ++r) oacc[g][mf][r] *= alpha;
    }

    __syncthreads();   // all waves done reading K-tile; safe to overlay P

    // ---- write P (per group: rows q=lane15, 64 keys; swizzled b64) ----
#pragma unroll
    for (int g = 0; g < 2; ++g) {
      bf16_t* Pw = lsK + (wave * 2 + g) * 1024;
#pragma unroll
      for (int mf = 0; mf < 4; ++mf) {
        const int c = mf * 2 + (quad >> 1);
        const int phys = c ^ (lane15 & 7);
        *(bf16x4*)(Pw + lane15 * 64 + phys * 8 + (quad & 1) * 4) = pk[g][mf];
      }
    }

    // ---- O^T += V^T @ P, both groups share each V fragment ----
#pragma unroll
    for (int kc = 0; kc < 2; ++kc) {
      const int cb = kc * 4 + quad;
      const int pb = cb ^ (lane15 & 7);
      bf16x8 bfr0 = *(const bf16x8*)(lsK + (wave * 2 + 0) * 1024 +
                                     lane15 * 64 + pb * 8);
      bf16x8 bfr1 = *(const bf16x8*)(lsK + (wave * 2 + 1) * 1024 +
                                     lane15 * 64 + pb * 8);
#pragma unroll
      for (int mf = 0; mf < 16; ++mf) {
        const int rr = mf * 16 + lane15;
        const int phys = cb ^ (rr & 7);
        bf16x8 af = *(const bf16x8*)(lsV + rr * 64 + phys * 8);
        oacc[0][mf] = __builtin_amdgcn_mfma_f32_16x16x32_bf16(af, bfr0,
                                                              oacc[0][mf], 0, 0, 0);
        oacc[1][mf] = __builtin_amdgcn_mfma_f32_16x16x32_bf16(af, bfr1,
                                                              oacc[1][mf], 0, 0, 0);
      }
    }
    __syncthreads();   // P/V reads done before next staging overwrites
  }

  // ---- write UNNORMALIZED partial O (fp32) + (m,l) per q-row ----
  const int b = z >> 2, head = z & 3;
#pragma unroll
  for (int g = 0; g < 2; ++g) {
    const int qrow = qt * 128 + wave * 32 + g * 16 + lane15;
    float* orow = Op + ((size_t)b * L_SEQ + qrow) * DMODEL + head * HDIM;
#pragma unroll
    for (int mf = 0; mf < 16; ++mf) {
      const int hd = mf * 16 + quad * 4;
      floatx4 ov = oacc[g][mf];
      *(floatx4*)(orow + hd) = ov;
    }
    if (quad == 0) {
      float* mlp = ml + ((size_t)(h * 16 + z) * L_SEQ + qrow) * 2;
      mlp[0] = m_run[g];
      mlp[1] = l_run[g];
    }
  }
}

// ---------------------------------------------------------------------------
// Combine two key-half partials: O = (O1*e^{m1-m} + O2*e^{m2-m}) / (l1' + l2')
// One thread per 4 output elems (same head => same z,row => same m,l).
// ---------------------------------------------------------------------------
__global__ __launch_bounds__(256)
void combine_attn(const float* __restrict__ Opart, const float* __restrict__ ml,
                  bf16_t* __restrict__ ob) {
  const int idx4 = blockIdx.x * 256 + threadIdx.x;   // float4 index
  const int row = idx4 >> 8;            // 256 float4 per 1024-row
  const int d = (idx4 & 255) * 4;
  const int head = d >> 8;
  const int b = row >> 11, l = row & 2047;
  const int z = b * NHEAD + head;
  const float* ml1 = ml + ((size_t)z * L_SEQ + l) * 2;
  const float* ml2 = ml + ((size_t)(16 + z) * L_SEQ + l) * 2;
  const float m1 = ml1[0], l1 = ml1[1], m2 = ml2[0], l2 = ml2[1];
  const float m = fmaxf(m1, m2);
  const float a1 = __expf(m1 - m), a2 = __expf(m2 - m);
  const float inv = 1.0f / (l1 * a1 + l2 * a2);
  const float4 o1 = ((const float4*)Opart)[idx4];
  const float4 o2 = ((const float4*)(Opart + (size_t)MROWS * DMODEL))[idx4];
  bf16x4 ov = { (bf16_t)((o1.x * a1 + o2.x * a2) * inv),
                (bf16_t)((o1.y * a1 + o2.y * a2) * inv),
                (bf16_t)((o1.z * a1 + o2.z * a2) * inv),
                (bf16_t)((o1.w * a1 + o2.w * a2) * inv) };
  ((bf16x4*)ob)[idx4] = ov;
}

// ---------------------------------------------------------------------------
// Epilogue functors — store4 gets 4 consecutive m (rows), fixed n
// ---------------------------------------------------------------------------
struct EpiBiasF32 {
  float* C; const float* bias; int ldc;
  __device__ __forceinline__ void store4(int, int m, int n, floatx4 v) const {
    const float bb = bias[n];
#pragma unroll
    for (int r = 0; r < 4; ++r) C[(size_t)(m + r) * ldc + n] = v[r] + bb;
  }
};
struct EpiResBiasF32 {
  float* C; const float* bias; int ldc;
  __device__ __forceinline__ void store4(int, int m, int n, floatx4 v) const {
    const float bb = bias[n];
#pragma unroll
    for (int r = 0; r < 4; ++r) {
      const size_t idx = (size_t)(m + r) * ldc + n;
      C[idx] = C[idx] + v[r] + bb;
    }
  }
};
struct EpiGeluBf16 {
  bf16_t* C; const float* bias; int ldc;
  __device__ __forceinline__ void store4(int, int m, int n, floatx4 v) const {
    const float bb = bias[n];
#pragma unroll
    for (int r = 0; r < 4; ++r) {
      const float t = v[r] + bb;
      const float g = 0.5f * t * (1.0f + erff(t * 0.7071067811865475f));
      C[(size_t)(m + r) * ldc + n] = (bf16_t)g;
    }
  }
};
struct EpiQKV {   // q,k -> (z,l,hd); v -> vT (z,hd,l) DIRECTLY TRANSPOSED
  bf16_t *q, *k, *vT; const float* bias;
  __device__ __forceinline__ void store4(int, int m, int n, floatx4 v) const {
    const float bb = bias[n];
    const int b = m >> 11, l = m & 2047;        // rows m..m+3 share b (m%4==0)
    const int which = n >> 10, e = n & 1023;
    const int head = e >> 8, hd = e & 255;
    const int z = b * NHEAD + head;
    if (which == 2) {
      bf16x4 ov = { (bf16_t)(v[0] + bb), (bf16_t)(v[1] + bb),
                    (bf16_t)(v[2] + bb), (bf16_t)(v[3] + bb) };
      *(bf16x4*)(vT + ((size_t)z * HDIM + hd) * L_SEQ + l) = ov;
    } else {
      bf16_t* dst = (which == 0 ? q : k) + ((size_t)z * L_SEQ + l) * HDIM + hd;
#pragma unroll
      for (int r = 0; r < 4; ++r) dst[(size_t)r * HDIM] = (bf16_t)(v[r] + bb);
    }
  }
};

// ---------------------------------------------------------------------------
// bf16 GEMM: C[m,n] = sum_k A[m,k]*B[n,k]  (B row-major NxK)
// BM=BN=128, BK=64; 4 waves 2x2, each 4x4 MFMA 16x16x32. XOR-swizzled LDS.
// ---------------------------------------------------------------------------
template<class Epi>
__global__ __launch_bounds__(256, 3)
void gemm_bt(const bf16_t* __restrict__ A, int lda, long strideA,
             const bf16_t* __restrict__ B, int ldb, long strideB,
             int K, Epi epi) {
  __shared__ bf16_t lsA[128 * 64];
  __shared__ bf16_t lsB[128 * 64];
  const int tid  = threadIdx.x;
  const int wave = tid >> 6, lane = tid & 63;
  const int z = blockIdx.z;
  A += (size_t)z * strideA;
  B += (size_t)z * strideB;
  const int m0 = blockIdx.y * 128, n0 = blockIdx.x * 128;

  const int rl = lane >> 3, p = lane & 7;
  const int csw = (p ^ rl) * 8;
  const int rbase = wave * 32 + rl;
  const bf16_t* gA = A + (size_t)(m0 + rbase) * lda + csw;
  const bf16_t* gB = B + (size_t)(n0 + rbase) * ldb + csw;
  bf16_t* lA = &lsA[wave * 32 * 64];
  bf16_t* lB = &lsB[wave * 32 * 64];

  const int wm = wave >> 1, wn = wave & 1;
  const int lane15 = lane & 15, quad = lane >> 4;
  const int arow = wm * 64 + lane15;
  const int brow = wn * 64 + lane15;
  const int sw = lane15 & 7;
  const int koff0 = ((quad + 0) ^ sw) * 8;
  const int koff1 = ((quad + 4) ^ sw) * 8;

  floatx4 acc[4][4] = {};

  for (int k0 = 0; k0 < K; k0 += 64) {
#pragma unroll
    for (int j = 0; j < 4; ++j) {
      async_cp16(gA + k0 + (size_t)j * 8 * lda, lA + j * 8 * 64);
      async_cp16(gB + k0 + (size_t)j * 8 * ldb, lB + j * 8 * 64);
    }
    __syncthreads();
#pragma unroll
    for (int kk = 0; kk < 2; ++kk) {
      const int ko = kk ? koff1 : koff0;
      bf16x8 af[4], bfr[4];
#pragma unroll
      for (int i = 0; i < 4; ++i)
        af[i] = *(const bf16x8*)&lsA[(arow + i * 16) * 64 + ko];
#pragma unroll
      for (int j = 0; j < 4; ++j)
        bfr[j] = *(const bf16x8*)&lsB[(brow + j * 16) * 64 + ko];
#pragma unroll
      for (int i = 0; i < 4; ++i)
#pragma unroll
        for (int j = 0; j < 4; ++j)
          acc[i][j] = __builtin_amdgcn_mfma_f32_16x16x32_bf16(af[i], bfr[j],
                                                              acc[i][j], 0, 0, 0);
    }
    __syncthreads();
  }

#pragma unroll
  for (int i = 0; i < 4; ++i) {
    const int mbase = m0 + wm * 64 + i * 16 + quad * 4;
#pragma unroll
    for (int j = 0; j < 4; ++j) {
      const int nloc = n0 + wn * 64 + j * 16 + lane15;
      epi.store4(z, mbase, nloc, acc[i][j]);
    }
  }
}

// ---------------------------------------------------------------------------
// Host launcher
// ---------------------------------------------------------------------------
extern "C" void kernel_launch(void* const* d_in, const int* in_sizes, int n_in,
                              void* d_out, int out_size, void* d_ws, size_t ws_size,
                              hipStream_t stream) {
  const float* x_in  = (const float*)d_in[0];
  const float* w3d   = (const float*)d_in[1];
  const float* b3d   = (const float*)d_in[2];
  const float* ln1g  = (const float*)d_in[3];
  const float* ln1b  = (const float*)d_in[4];
  const float* wqkv  = (const float*)d_in[5];
  const float* bqkv  = (const float*)d_in[6];
  const float* wproj = (const float*)d_in[7];
  const float* bproj = (const float*)d_in[8];
  const float* ln2g  = (const float*)d_in[9];
  const float* ln2b  = (const float*)d_in[10];
  const float* w1    = (const float*)d_in[11];
  const float* b1    = (const float*)d_in[12];
  const float* w2    = (const float*)d_in[13];
  const float* b2    = (const float*)d_in[14];
  const float* lnfg  = (const float*)d_in[15];
  const float* lnfb  = (const float*)d_in[16];
  float* out = (float*)d_out;

  char* ws = (char*)d_ws;
  size_t off = 0;
  auto alloc = [&](size_t bytes) -> void* {
    void* p = ws + off;
    off = (off + bytes + 255) & ~(size_t)255;
    return p;
  };
  float*  h      = (float*) alloc((size_t)MROWS * DMODEL * 4);        // 32 MB
  bf16_t* hn     = (bf16_t*)alloc((size_t)MROWS * DMODEL * 2);        // 16 MB
  bf16_t* w3db   = (bf16_t*)alloc((size_t)DMODEL * 3 * DMODEL * 2);
  bf16_t* wqkvb  = (bf16_t*)alloc((size_t)NLAYER * 3 * DMODEL * DMODEL * 2);
  bf16_t* wprojb = (bf16_t*)alloc((size_t)NLAYER * DMODEL * DMODEL * 2);
  bf16_t* w1b    = (bf16_t*)alloc((size_t)NLAYER * FFDIM * DMODEL * 2);
  bf16_t* w2b    = (bf16_t*)alloc((size_t)NLAYER * DMODEL * FFDIM * 2);
  bf16_t* xb     = (bf16_t*)alloc((size_t)MROWS * 3 * DMODEL * 2);    // 48 MB
  bf16_t* qb     = (bf16_t*)alloc((size_t)MROWS * DMODEL * 2);        // 16 MB
  bf16_t* kb     = (bf16_t*)alloc((size_t)MROWS * DMODEL * 2);        // 16 MB
  bf16_t* vT     = (bf16_t*)alloc((size_t)MROWS * DMODEL * 2);        // 16 MB
  bf16_t* ob     = (bf16_t*)alloc((size_t)MROWS * DMODEL * 2);        // 16 MB
  bf16_t* f      = (bf16_t*)alloc((size_t)MROWS * FFDIM * 2);         // 64 MB
  float*  ml     = (float*) alloc(2ull * 16 * L_SEQ * 2 * 4);         // 512 KB
  // Opart (2 x 32MB fp32) overlays f (64MB): attention finishes before FF1.
  float*  Opart  = (float*)f;
  (void)ws_size; (void)in_sizes; (void)n_in; (void)out_size;

  auto cvt = [&](const float* src, bf16_t* dst, size_t n) {
    int n4 = (int)(n / 4);
    cvt_f32_bf16<<<(n4 + 255) / 256, 256, 0, stream>>>(src, dst, n4);
  };
  cvt(x_in,  xb,     (size_t)MROWS * 3 * DMODEL);
  cvt(w3d,   w3db,   (size_t)DMODEL * 3 * DMODEL);
  cvt(wqkv,  wqkvb,  (size_t)NLAYER * 3 * DMODEL * DMODEL);
  cvt(wproj, wprojb, (size_t)NLAYER * DMODEL * DMODEL);
  cvt(w1,    w1b,    (size_t)NLAYER * FFDIM * DMODEL);
  cvt(w2,    w2b,    (size_t)NLAYER * DMODEL * FFDIM);

  // initial projection: h = x @ w3d^T + b3d
  gemm_bt<<<dim3(DMODEL / 128, MROWS / 128, 1), 256, 0, stream>>>(
      xb, 3 * DMODEL, 0L, w3db, 3 * DMODEL, 0L, 3 * DMODEL,
      EpiBiasF32{h, b3d, DMODEL});

  for (int i = 0; i < NLAYER; ++i) {
    ln_kernel<true><<<MROWS, 256, 0, stream>>>(h, ln1g + i * DMODEL,
                                               ln1b + i * DMODEL, hn);
    // qkv: q,k -> (z,l,hd); v -> vT (z,hd,l) transposed in epilogue
    gemm_bt<<<dim3(3 * DMODEL / 128, MROWS / 128, 1), 256, 0, stream>>>(
        hn, DMODEL, 0L, wqkvb + (size_t)i * 3 * DMODEL * DMODEL, DMODEL, 0L,
        DMODEL, EpiQKV{qb, kb, vT, bqkv + i * 3 * DMODEL});
    // flash attention, key-split into 2 halves -> partial O + (m,l)
    flash_attn<<<dim3(L_SEQ / 128, BATCH * NHEAD, 2), 256, 0, stream>>>(
        qb, kb, vT, Opart, ml);
    combine_attn<<<(MROWS * DMODEL / 4) / 256, 256, 0, stream>>>(Opart, ml, ob);
    gemm_bt<<<dim3(DMODEL / 128, MROWS / 128, 1), 256, 0, stream>>>(
        ob, DMODEL, 0L, wprojb + (size_t)i * DMODEL * DMODEL, DMODEL, 0L,
        DMODEL, EpiResBiasF32{h, bproj + i * DMODEL, DMODEL});
    ln_kernel<true><<<MROWS, 256, 0, stream>>>(h, ln2g + i * DMODEL,
                                               ln2b + i * DMODEL, hn);
    gemm_bt<<<dim3(FFDIM / 128, MROWS / 128, 1), 256, 0, stream>>>(
        hn, DMODEL, 0L, w1b + (size_t)i * FFDIM * DMODEL, DMODEL, 0L, DMODEL,
        EpiGeluBf16{f, b1 + i * FFDIM, FFDIM});
    gemm_bt<<<dim3(DMODEL / 128, MROWS / 128, 1), 256, 0, stream>>>(
        f, FFDIM, 0L, w2b + (size_t)i * DMODEL * FFDIM, FFDIM, 0L, FFDIM,
        EpiResBiasF32{h, b2 + i * DMODEL, DMODEL});
  }

  ln_kernel<false><<<MROWS, 256, 0, stream>>>(h, lnfg, lnfb, out);
}